// Round 7
// baseline (177.712 us; speedup 1.0000x reference)
//
#include <hip/hip_runtime.h>
#include <hip/hip_bf16.h>
#include <hip/hip_fp16.h>
#include <math.h>

typedef _Float16 f16;
typedef _Float16 f16x8 __attribute__((ext_vector_type(8)));
typedef _Float16 f16x4 __attribute__((ext_vector_type(4)));
typedef _Float16 f16x2 __attribute__((ext_vector_type(2)));
typedef unsigned short u16x8v __attribute__((ext_vector_type(8)));
typedef float f32x4 __attribute__((ext_vector_type(4)));

namespace {
constexpr int B = 2;
constexpr int H = 16;
constexpr int S = 2048;
constexpr int D = 64;
constexpr int E = 1024;
// fold 1/sqrt(64) * log2(e) into Q so softmax uses exp2 directly
constexpr float QSCALE = 0.125f * 1.4426950408889634f;
}

#define GLOBAL_LOAD_LDS16(gp, lp)                                              \
  __builtin_amdgcn_global_load_lds(                                            \
      (const __attribute__((address_space(1))) void*)(gp),                     \
      (__attribute__((address_space(3))) void*)(lp), 16, 0, 0)

// ---------- prep: [blocks 0..1023] Wd fp32->f16 ; [blocks 1024..1039] Wkv = Wk*Wv, bkv = Wk*bv + bk
__global__ __launch_bounds__(256) void prep(const float* __restrict__ Wd, f16* __restrict__ wd16,
                                            const float* __restrict__ Wk, const float* __restrict__ Wv,
                                            const float* __restrict__ bv, const float* __restrict__ bk,
                                            float* __restrict__ Wkv, float* __restrict__ bkv) {
  if (blockIdx.x < 1024) {
    const int i = blockIdx.x * 256 + threadIdx.x;
    const float4 f = ((const float4*)Wd)[i];
    f16x4 o;
    o.x = (f16)f.x; o.y = (f16)f.y; o.z = (f16)f.z; o.w = (f16)f.w;
    *(f16x4*)(wd16 + 4 * (size_t)i) = o;
  } else {
    const int g = (blockIdx.x - 1024) * 256 + threadIdx.x;   // 0..4095
    const int i = g >> 6, j = g & 63;
    float s = 0.f;
#pragma unroll 16
    for (int d = 0; d < 64; ++d) s = fmaf(Wk[i * 64 + d], Wv[d * 64 + j], s);
    Wkv[g] = s;
    if (g < 64) {
      float bb = bk[g];
#pragma unroll 16
      for (int d = 0; d < 64; ++d) bb = fmaf(Wk[g * 64 + d], bv[d], bb);
      bkv[g] = bb;
    }
  }
}

// ---------- projections: blockIdx.y==0 -> Q; ==1 -> V then K (x loaded once, two weight passes).
// Q output: [b][s][h][d] (natural C-fragment order -> coalesced stores; attn adapts its read).
// K output: [b][h][s][d] via LDS bounce (coalesced stores).
// V output: transposed+permuted vtp[b][h][d][S] (as R5).
__global__ __launch_bounds__(256) void proj3_mfma(const float* __restrict__ xq,
                                                  const float* __restrict__ xv,
                                                  const float* __restrict__ Wq,
                                                  const float* __restrict__ bq,
                                                  const float* __restrict__ Wv,
                                                  const float* __restrict__ bv,
                                                  const float* __restrict__ Wkv,
                                                  const float* __restrict__ bkv,
                                                  f16* __restrict__ qp,
                                                  f16* __restrict__ vtp,
                                                  f16* __restrict__ kp) {
  __shared__ f16 tb[16 * 16 * 68];   // 34.8 KB bounce (V: [pi][16]; K: [h*16+sl][68])
  const int which = blockIdx.y;
  const float* x = which ? xv : xq;

  const int t = threadIdx.x, lane = t & 63, w = t >> 6;
  const int l15 = lane & 15, quad = lane >> 4;
  const int m0 = (blockIdx.x * 4 + w) * 64;

  f16x8 af[4][2];
#pragma unroll
  for (int mt = 0; mt < 4; ++mt)
#pragma unroll
    for (int kc = 0; kc < 2; ++kc) {
      const float* g = x + (size_t)(m0 + mt * 16 + l15) * 64 + kc * 32 + quad * 8;
      const float4 a = *(const float4*)g, b2 = *(const float4*)(g + 4);
      f16x8 v;
      v[0]=(f16)a.x; v[1]=(f16)a.y; v[2]=(f16)a.z; v[3]=(f16)a.w;
      v[4]=(f16)b2.x; v[5]=(f16)b2.y; v[6]=(f16)b2.z; v[7]=(f16)b2.w;
      af[mt][kc] = v;
    }

  const int npass = which ? 2 : 1;
  for (int pass = 0; pass < npass; ++pass) {
    const float* W    = which ? (pass ? Wkv : Wv) : Wq;
    const float* bias = which ? (pass ? bkv : bv) : bq;
    const bool vpass  = (which == 1) && (pass == 0);
    const bool kpass  = (which == 1) && (pass == 1);
    const float scale = which ? 1.0f : QSCALE;

    f16x8 wf[4][2];
#pragma unroll
    for (int nt = 0; nt < 4; ++nt)
#pragma unroll
      for (int kc = 0; kc < 2; ++kc) {
        const float* g = W + (size_t)(nt * 16 + l15) * 64 + kc * 32 + quad * 8;
        const float4 a = *(const float4*)g, b2 = *(const float4*)(g + 4);
        f16x8 v;
        v[0]=(f16)a.x; v[1]=(f16)a.y; v[2]=(f16)a.z; v[3]=(f16)a.w;
        v[4]=(f16)b2.x; v[5]=(f16)b2.y; v[6]=(f16)b2.z; v[7]=(f16)b2.w;
        wf[nt][kc] = v;
      }

    f32x4 acc[4][4];   // [nt][mt]
#pragma unroll
    for (int nt = 0; nt < 4; ++nt)
#pragma unroll
      for (int mt = 0; mt < 4; ++mt) acc[nt][mt] = (f32x4){0.f, 0.f, 0.f, 0.f};
#pragma unroll
    for (int kc = 0; kc < 2; ++kc)
#pragma unroll
      for (int nt = 0; nt < 4; ++nt)
#pragma unroll
        for (int mt = 0; mt < 4; ++mt)
          acc[nt][mt] = __builtin_amdgcn_mfma_f32_16x16x32_f16(wf[nt][kc], af[mt][kc], acc[nt][mt], 0, 0, 0);

    float4 bl4[4];
#pragma unroll
    for (int nt = 0; nt < 4; ++nt) bl4[nt] = *(const float4*)&bias[nt * 16 + quad * 4];

#pragma unroll
    for (int mt = 0; mt < 4; ++mt) {
      const int g = m0 + mt * 16 + l15;   // (b*S+s)*H + h
#pragma unroll
      for (int nt = 0; nt < 4; ++nt) {
        const float p0 = (acc[nt][mt][0] + bl4[nt].x) * scale;
        const float p1 = (acc[nt][mt][1] + bl4[nt].y) * scale;
        const float p2 = (acc[nt][mt][2] + bl4[nt].z) * scale;
        const float p3 = (acc[nt][mt][3] + bl4[nt].w) * scale;
        union { f16x4 v4; f16x2 hh[2]; } u;
        u.hh[0] = __builtin_bit_cast(f16x2, __builtin_amdgcn_cvt_pkrtz(p0, p1));
        u.hh[1] = __builtin_bit_cast(f16x2, __builtin_amdgcn_cvt_pkrtz(p2, p3));
        if (vpass) {
          // tb[pi][sl]: pi = h*64 + d, h=l15, d=nt*16+quad*4+r, sl=w*4+mt
#pragma unroll
          for (int r = 0; r < 4; ++r)
            tb[(l15 * 64 + nt * 16 + quad * 4 + r) * 16 + w * 4 + mt] = u.v4[r];
        } else if (kpass) {
          // tb[h*16+sl][68]: coalesced-store bounce
          *(f16x4*)&tb[(l15 * 16 + w * 4 + mt) * 68 + nt * 16 + quad * 4] = u.v4;
        } else {
          // Q: natural layout [b][s][h][d] = row g -> coalesced
          *(f16x4*)(qp + (size_t)g * 64 + nt * 16 + quad * 4) = u.v4;
        }
      }
    }

    if (vpass) {
      __syncthreads();
      const int bsb = blockIdx.x * 16;
      const int bb = bsb >> 11;
      const int sb = bsb & 2047;
      const int off = sb & 63;                              // in {0,16,32,48}
      const int poff = (off & 32) | ((off & 16) >> 2);      // perm-inverse of the off bits
      const int col0 = (sb - off) + poff;
#pragma unroll
      for (int k2 = 0; k2 < 4; ++k2) {
        const int pi = t * 4 + k2;                          // (h,d) pair
        const int h = pi >> 6, d = pi & 63;
        const f16x8 lo = *(const f16x8*)&tb[pi * 16];
        const f16x8 hi = *(const f16x8*)&tb[pi * 16 + 8];
        f16* orow = vtp + ((size_t)(bb * H + h) * 64 + d) * S + col0;
        f16x4 g0, g1, g2, g3;
#pragma unroll
        for (int j = 0; j < 4; ++j) { g0[j]=lo[j]; g1[j]=lo[4+j]; g2[j]=hi[j]; g3[j]=hi[4+j]; }
        *(f16x4*)(orow + 0)  = g0;
        *(f16x4*)(orow + 8)  = g1;
        *(f16x4*)(orow + 16) = g2;
        *(f16x4*)(orow + 24) = g3;
      }
      __syncthreads();
    } else if (kpass) {
      __syncthreads();
      // writeout: thread t -> h = t>>4, sl = t&15: 64 contiguous f16 to kp[b][h][s][d]
      const int bsb = blockIdx.x * 16;
      const int bb = bsb >> 11;
      const int sblk = bsb & 2047;
      const int h = t >> 4, sl = t & 15;
      f16* dst = kp + ((size_t)(bb * H + h) * S + sblk + sl) * 64;
      const f16* src = &tb[t * 68];
#pragma unroll
      for (int c = 0; c < 8; ++c)
        *(f16x8*)(dst + c * 8) = *(const f16x8*)(src + c * 8);
    }
  }
}

// ---------- MFMA flash attention v7: KVBLK=128 (16 steps -> half the sync events),
// depth-2 LDS via global_load_lds (issue-after-barrier, loads hidden under full tile),
// in-register P (swapped QK^T + V permutation), XOR chunk swizzle, setprio on MFMA.
// Q read from [b][s][h][d]; K [b][h][s][d]; V^T [b][h][d][S] permuted.
// pa[mt][kc][j] = exp2(sc[2kc+(j>>2)][mt][j&3]) for kc 0..3 (verified for 128-kv tiles).
__global__ __launch_bounds__(256) void attn_mfma(const f16* __restrict__ qp,
                                                 const f16* __restrict__ kp,
                                                 const f16* __restrict__ vtp,
                                                 f16* __restrict__ ao) {
  __shared__ f16 ks[2][128 * 64];   // 16 KB/buf: K tile [kv][d-chunks], LDS[r][c]=glob chunk c^(r&7)
  __shared__ f16 vs[2][64 * 128];   // 16 KB/buf: V^T tile [d][p-chunks], same swizzle (16 chunks/row)
  const int t = threadIdx.x, lane = t & 63, w = t >> 6;
  const int l15 = lane & 15, quad = lane >> 4;
  const int bh = blockIdx.x;
  const int b = bh >> 4, h = bh & 15;
  const int q0 = blockIdx.y * 128;
  const f16* kbase = kp + (size_t)bh * S * D;
  const f16* vtbase = vtp + (size_t)bh * 64 * S;

  // staging geometry: base chunk c1 = w*64 + lane; call i adds 256 chunks.
  const int c1 = w * 64 + lane;
  const int krow = c1 >> 3;                       // K: 8 chunks/row
  const size_t koff1 = (size_t)krow * D + (((c1 & 7) ^ (krow & 7)) * 8);
  const int vrow = c1 >> 4;                       // V: 16 chunks/row
  const size_t voff1 = (size_t)vrow * S + (((c1 & 15) ^ (vrow & 7)) * 8);

  f16x8 qf[2][2];
#pragma unroll
  for (int mt = 0; mt < 2; ++mt)
#pragma unroll
    for (int kc = 0; kc < 2; ++kc)
      qf[mt][kc] = *(const f16x8*)(qp +
          ((size_t)(b * S + q0 + w * 32 + mt * 16 + l15) * H + h) * 64 + kc * 32 + quad * 8);

  // ones-column B-frag: B[k][n]=1 for n==0 -> row-sum (l) accumulates in O[mt][4] col 0
  f16x8 vb4;
#pragma unroll
  for (int j = 0; j < 8; ++j) vb4[j] = (l15 == 0) ? (f16)1.0f : (f16)0.0f;

  f32x4 O[2][5];
#pragma unroll
  for (int mt = 0; mt < 2; ++mt)
#pragma unroll
    for (int nt = 0; nt < 5; ++nt) O[mt][nt] = (f32x4){0.f, 0.f, 0.f, 0.f};

#define ISSUE_TILE(tt, buf)                                                    \
  {                                                                            \
    const f16* gk = kbase + (size_t)(tt) * (128 * D);                          \
    _Pragma("unroll")                                                          \
    for (int i = 0; i < 4; ++i)                                                \
      GLOBAL_LOAD_LDS16(gk + koff1 + (size_t)i * (32 * D),                     \
                        &ks[buf][(i * 256 + w * 64) * 8]);                     \
    const f16* gv = vtbase + (size_t)(tt) * 128;                               \
    _Pragma("unroll")                                                          \
    for (int i = 0; i < 4; ++i)                                                \
      GLOBAL_LOAD_LDS16(gv + voff1 + (size_t)i * (16 * S),                     \
                        &vs[buf][(i * 256 + w * 64) * 8]);                     \
  }

  ISSUE_TILE(0, 0);

  for (int kt = 0; kt < S / 128; ++kt) {
    const int rb = kt & 1;
    // loads of tile kt (issued a full tile ago) complete; barrier also closes all
    // reads of buffer rb^1 (tile kt-1) -> safe to issue kt+1 into it after.
    __asm__ volatile("s_waitcnt vmcnt(0)" ::: "memory");
    __builtin_amdgcn_s_barrier();
    __asm__ volatile("" ::: "memory");
    if (kt + 1 < S / 128) ISSUE_TILE(kt + 1, rb ^ 1);

    // QK^T swapped: sc[nt][mt] = mfma(K-frag, Q-frag) -> C[kv][q], q = l15 lane-local
    f32x4 sc[8][2];
#pragma unroll
    for (int nt = 0; nt < 8; ++nt)
#pragma unroll
      for (int mt = 0; mt < 2; ++mt) sc[nt][mt] = (f32x4){0.f, 0.f, 0.f, 0.f};
    __builtin_amdgcn_s_setprio(1);
#pragma unroll
    for (int kc = 0; kc < 2; ++kc)
#pragma unroll
      for (int nt = 0; nt < 8; ++nt) {
        const f16x8 kf = *(const f16x8*)&ks[rb][(nt * 16 + l15) * 64 + (((kc * 4 + quad) ^ (l15 & 7)) * 8)];
#pragma unroll
        for (int mt = 0; mt < 2; ++mt)
          sc[nt][mt] = __builtin_amdgcn_mfma_f32_16x16x32_f16(kf, qf[mt][kc], sc[nt][mt], 0, 0, 0);
      }
    __builtin_amdgcn_s_setprio(0);

    // P = exp2(sc) packed straight into PV A-frags (in-register)
    f16x8 pa[2][4];
#pragma unroll
    for (int mt = 0; mt < 2; ++mt)
#pragma unroll
      for (int kc = 0; kc < 4; ++kc) {
        const f32x4 s0 = sc[2 * kc][mt], s1 = sc[2 * kc + 1][mt];
        union { f16x8 v8; f16x2 hh[4]; } u;
        u.hh[0] = __builtin_bit_cast(f16x2, __builtin_amdgcn_cvt_pkrtz(
            __builtin_amdgcn_exp2f(s0[0]), __builtin_amdgcn_exp2f(s0[1])));
        u.hh[1] = __builtin_bit_cast(f16x2, __builtin_amdgcn_cvt_pkrtz(
            __builtin_amdgcn_exp2f(s0[2]), __builtin_amdgcn_exp2f(s0[3])));
        u.hh[2] = __builtin_bit_cast(f16x2, __builtin_amdgcn_cvt_pkrtz(
            __builtin_amdgcn_exp2f(s1[0]), __builtin_amdgcn_exp2f(s1[1])));
        u.hh[3] = __builtin_bit_cast(f16x2, __builtin_amdgcn_cvt_pkrtz(
            __builtin_amdgcn_exp2f(s1[2]), __builtin_amdgcn_exp2f(s1[3])));
        pa[mt][kc] = u.v8;
      }

    // PV += P * V (phys-k order matches vtp perm); l accumulates in O[mt][4] col 0
    __builtin_amdgcn_s_setprio(1);
#pragma unroll
    for (int kc = 0; kc < 4; ++kc) {
#pragma unroll
      for (int nt = 0; nt < 4; ++nt) {
        const f16x8 vbf = *(const f16x8*)&vs[rb][(nt * 16 + l15) * 128 + (((kc * 4 + quad) ^ (l15 & 7)) * 8)];
#pragma unroll
        for (int mt = 0; mt < 2; ++mt)
          O[mt][nt] = __builtin_amdgcn_mfma_f32_16x16x32_f16(pa[mt][kc], vbf, O[mt][nt], 0, 0, 0);
      }
#pragma unroll
      for (int mt = 0; mt < 2; ++mt)
        O[mt][4] = __builtin_amdgcn_mfma_f32_16x16x32_f16(pa[mt][kc], vb4, O[mt][4], 0, 0, 0);
    }
    __builtin_amdgcn_s_setprio(0);
  }
#undef ISSUE_TILE

  // epilogue: l lives in lane group's l15==0 lane of O[mt][4]
#pragma unroll
  for (int mt = 0; mt < 2; ++mt)
#pragma unroll
    for (int r = 0; r < 4; ++r) {
      const float l = __shfl(O[mt][4][r], quad << 4, 64);
      const float inv = 1.f / l;
      const int row = q0 + w * 32 + mt * 16 + quad * 4 + r;
      f16* o = ao + ((size_t)b * S + row) * E + h * D;
#pragma unroll
      for (int nt = 0; nt < 4; ++nt)
        o[nt * 16 + l15] = (f16)(O[mt][nt][r] * inv);
    }
}

// ---------- dense: out[m][n] = sum_e A[m][e] * Wd16[n][e] + bd[n]
// BM=128, BN=64, triple-buffered, counted vmcnt(6) + raw barrier. 2 blocks/CU.
__global__ __launch_bounds__(256) void dense_mfma(const f16* __restrict__ A,
                                                  const f16* __restrict__ Wd16,
                                                  const float* __restrict__ bd,
                                                  float* __restrict__ out) {
  __shared__ f16 as[3][128 * 64];   // 48 KB
  __shared__ f16 bs[3][64 * 64];    // 24 KB
  const int t = threadIdx.x;
  const int lane = t & 63;
  const int w = t >> 6;
  const int l15 = lane & 15;
  const int quad = lane >> 4;
  const int m0 = blockIdx.x * 128;
  const int n0 = blockIdx.y * 64;
  const int wm = (w >> 1) * 64, wn = (w & 1) * 32;   // wave tile 64x32

  const int srow = (lane >> 3);
  const int schunk = (lane & 7) ^ srow;
  const f16* ga0 = A    + (size_t)(m0 + w * 32 + srow) * E + schunk * 8;
  const f16* gb0 = Wd16 + (size_t)(n0 + w * 16 + srow) * E + schunk * 8;

  constexpr int NT = E / 64;

#define ISSUE_D(tt, ib)                                                        \
  {                                                                            \
    _Pragma("unroll")                                                          \
    for (int i = 0; i < 4; ++i)                                                \
      GLOBAL_LOAD_LDS16(ga0 + (size_t)(i * 8) * E + (tt) * 64,                 \
                        &as[ib][(w * 32 + i * 8) * 64]);                       \
    _Pragma("unroll")                                                          \
    for (int i = 0; i < 2; ++i)                                                \
      GLOBAL_LOAD_LDS16(gb0 + (size_t)(i * 8) * E + (tt) * 64,                 \
                        &bs[ib][(w * 16 + i * 8) * 64]);                       \
  }

  f32x4 acc[4][2];
#pragma unroll
  for (int mt = 0; mt < 4; ++mt)
#pragma unroll
    for (int nt = 0; nt < 2; ++nt) acc[mt][nt] = (f32x4){0.f, 0.f, 0.f, 0.f};

  ISSUE_D(0, 0);
  ISSUE_D(1, 1);
  __asm__ volatile("s_waitcnt vmcnt(6)" ::: "memory");
  __builtin_amdgcn_s_barrier();
  __asm__ volatile("" ::: "memory");

  int rb = 0, ib = 2;
  for (int kt = 0; kt < NT; ++kt) {
    {
      const int tt = (kt + 2 < NT) ? (kt + 2) : (NT - 1);
      ISSUE_D(tt, ib);
    }
    f16x8 af[4][2];
#pragma unroll
    for (int mt = 0; mt < 4; ++mt)
#pragma unroll
      for (int kc = 0; kc < 2; ++kc)
        af[mt][kc] = *(const f16x8*)&as[rb][(wm + mt * 16 + l15) * 64 + (((kc * 4 + quad) ^ (l15 & 7)) * 8)];
#pragma unroll
    for (int kc = 0; kc < 2; ++kc)
#pragma unroll
      for (int nt = 0; nt < 2; ++nt) {
        const f16x8 bf = *(const f16x8*)&bs[rb][(wn + nt * 16 + l15) * 64 + (((kc * 4 + quad) ^ (l15 & 7)) * 8)];
#pragma unroll
        for (int mt = 0; mt < 4; ++mt)
          acc[mt][nt] = __builtin_amdgcn_mfma_f32_16x16x32_f16(af[mt][kc], bf, acc[mt][nt], 0, 0, 0);
      }
    __asm__ volatile("s_waitcnt vmcnt(6)" ::: "memory");
    __builtin_amdgcn_s_barrier();
    __asm__ volatile("" ::: "memory");
    rb = (rb + 1 >= 3) ? 0 : rb + 1;
    ib = (ib + 1 >= 3) ? 0 : ib + 1;
  }
#undef ISSUE_D

#pragma unroll
  for (int nt = 0; nt < 2; ++nt) {
    const int col = n0 + wn + nt * 16 + l15;
    const float bdv = bd[col];
#pragma unroll
    for (int mt = 0; mt < 4; ++mt)
#pragma unroll
      for (int r = 0; r < 4; ++r)
        out[(size_t)(m0 + wm + mt * 16 + quad * 4 + r) * E + col] = acc[mt][nt][r] + bdv;
  }
}

extern "C" void kernel_launch(void* const* d_in, const int* in_sizes, int n_in,
                              void* d_out, int out_size, void* d_ws, size_t ws_size,
                              hipStream_t stream) {
  const float* queries = (const float*)d_in[0];
  const float* values  = (const float*)d_in[1];
  const float* Wv = (const float*)d_in[3];
  const float* bv = (const float*)d_in[4];
  const float* Wk = (const float*)d_in[5];
  const float* bk = (const float*)d_in[6];
  const float* Wq = (const float*)d_in[7];
  const float* bq = (const float*)d_in[8];
  const float* Wd = (const float*)d_in[9];
  const float* bd = (const float*)d_in[10];
  float* out = (float*)d_out;

  char* ws = (char*)d_ws;
  f16* qp    = (f16*)(ws);                          // 8 MB [B,S,H,D]  (natural layout)
  f16* kp    = (f16*)(ws + 8u * 1024 * 1024);       // 8 MB [B,H,S,D]
  f16* vtp   = (f16*)(ws + 16u * 1024 * 1024);      // 8 MB [B,H,D,S] permuted V^T
  f16* ao    = (f16*)(ws + 24u * 1024 * 1024);      // 8 MB [B,S,E]
  f16* wd16  = (f16*)(ws + 32u * 1024 * 1024);      // 2 MB
  float* wkv = (float*)(ws + 34u * 1024 * 1024);    // 16 KB
  float* bkv = (float*)(ws + 34u * 1024 * 1024 + 16384);
  (void)ws_size; (void)in_sizes; (void)n_in; (void)out_size;

  prep<<<1040, 256, 0, stream>>>(Wd, wd16, Wk, Wv, bv, bk, wkv, bkv);
  proj3_mfma<<<dim3(256, 2), 256, 0, stream>>>(queries, values, Wq, bq, Wv, bv, wkv, bkv, qp, vtp, kp);
  attn_mfma<<<dim3(B * H, S / 128), 256, 0, stream>>>(qp, kp, vtp, ao);
  dense_mfma<<<dim3(B * S / 128, E / 64), 256, 0, stream>>>(ao, wd16, bd, out);
}

// Round 8
// 177.657 us; speedup vs baseline: 1.0003x; 1.0003x over previous
//
#include <hip/hip_runtime.h>
#include <hip/hip_bf16.h>
#include <hip/hip_fp16.h>
#include <math.h>

typedef _Float16 f16;
typedef _Float16 f16x8 __attribute__((ext_vector_type(8)));
typedef _Float16 f16x4 __attribute__((ext_vector_type(4)));
typedef _Float16 f16x2 __attribute__((ext_vector_type(2)));
typedef unsigned short u16x8v __attribute__((ext_vector_type(8)));
typedef float f32x4 __attribute__((ext_vector_type(4)));

namespace {
constexpr int B = 2;
constexpr int H = 16;
constexpr int S = 2048;
constexpr int D = 64;
constexpr int E = 1024;
// fold 1/sqrt(64) * log2(e) into Q so softmax uses exp2 directly
constexpr float QSCALE = 0.125f * 1.4426950408889634f;
}

#define GLOBAL_LOAD_LDS16(gp, lp)                                              \
  __builtin_amdgcn_global_load_lds(                                            \
      (const __attribute__((address_space(1))) void*)(gp),                     \
      (__attribute__((address_space(3))) void*)(lp), 16, 0, 0)

// ---------- prep: [blocks 0..1023] Wd fp32->f16 ; [blocks 1024..1039] Wkv = Wk*Wv, bkv = Wk*bv + bk
__global__ __launch_bounds__(256) void prep(const float* __restrict__ Wd, f16* __restrict__ wd16,
                                            const float* __restrict__ Wk, const float* __restrict__ Wv,
                                            const float* __restrict__ bv, const float* __restrict__ bk,
                                            float* __restrict__ Wkv, float* __restrict__ bkv) {
  if (blockIdx.x < 1024) {
    const int i = blockIdx.x * 256 + threadIdx.x;
    const float4 f = ((const float4*)Wd)[i];
    f16x4 o;
    o.x = (f16)f.x; o.y = (f16)f.y; o.z = (f16)f.z; o.w = (f16)f.w;
    *(f16x4*)(wd16 + 4 * (size_t)i) = o;
  } else {
    const int g = (blockIdx.x - 1024) * 256 + threadIdx.x;   // 0..4095
    const int i = g >> 6, j = g & 63;
    float s = 0.f;
#pragma unroll 16
    for (int d = 0; d < 64; ++d) s = fmaf(Wk[i * 64 + d], Wv[d * 64 + j], s);
    Wkv[g] = s;
    if (g < 64) {
      float bb = bk[g];
#pragma unroll 16
      for (int d = 0; d < 64; ++d) bb = fmaf(Wk[g * 64 + d], bv[d], bb);
      bkv[g] = bb;
    }
  }
}

// ---------- projections: blockIdx.y==0 -> Q; ==1 -> V then K (x loaded once, two weight passes).
// Q output: [b][s][h][d] (natural C-fragment order -> coalesced stores; attn adapts its read).
// K output: [b][h][s][d] via LDS bounce (coalesced stores).
// V output: transposed+permuted vtp[b][h][d][S] (as R5).
__global__ __launch_bounds__(256) void proj3_mfma(const float* __restrict__ xq,
                                                  const float* __restrict__ xv,
                                                  const float* __restrict__ Wq,
                                                  const float* __restrict__ bq,
                                                  const float* __restrict__ Wv,
                                                  const float* __restrict__ bv,
                                                  const float* __restrict__ Wkv,
                                                  const float* __restrict__ bkv,
                                                  f16* __restrict__ qp,
                                                  f16* __restrict__ vtp,
                                                  f16* __restrict__ kp) {
  __shared__ f16 tb[16 * 16 * 68];   // 34.8 KB bounce (V: [pi][16]; K: [h*16+sl][68])
  const int which = blockIdx.y;
  const float* x = which ? xv : xq;

  const int t = threadIdx.x, lane = t & 63, w = t >> 6;
  const int l15 = lane & 15, quad = lane >> 4;
  const int m0 = (blockIdx.x * 4 + w) * 64;

  f16x8 af[4][2];
#pragma unroll
  for (int mt = 0; mt < 4; ++mt)
#pragma unroll
    for (int kc = 0; kc < 2; ++kc) {
      const float* g = x + (size_t)(m0 + mt * 16 + l15) * 64 + kc * 32 + quad * 8;
      const float4 a = *(const float4*)g, b2 = *(const float4*)(g + 4);
      f16x8 v;
      v[0]=(f16)a.x; v[1]=(f16)a.y; v[2]=(f16)a.z; v[3]=(f16)a.w;
      v[4]=(f16)b2.x; v[5]=(f16)b2.y; v[6]=(f16)b2.z; v[7]=(f16)b2.w;
      af[mt][kc] = v;
    }

  const int npass = which ? 2 : 1;
  for (int pass = 0; pass < npass; ++pass) {
    const float* W    = which ? (pass ? Wkv : Wv) : Wq;
    const float* bias = which ? (pass ? bkv : bv) : bq;
    const bool vpass  = (which == 1) && (pass == 0);
    const bool kpass  = (which == 1) && (pass == 1);
    const float scale = which ? 1.0f : QSCALE;

    f16x8 wf[4][2];
#pragma unroll
    for (int nt = 0; nt < 4; ++nt)
#pragma unroll
      for (int kc = 0; kc < 2; ++kc) {
        const float* g = W + (size_t)(nt * 16 + l15) * 64 + kc * 32 + quad * 8;
        const float4 a = *(const float4*)g, b2 = *(const float4*)(g + 4);
        f16x8 v;
        v[0]=(f16)a.x; v[1]=(f16)a.y; v[2]=(f16)a.z; v[3]=(f16)a.w;
        v[4]=(f16)b2.x; v[5]=(f16)b2.y; v[6]=(f16)b2.z; v[7]=(f16)b2.w;
        wf[nt][kc] = v;
      }

    f32x4 acc[4][4];   // [nt][mt]
#pragma unroll
    for (int nt = 0; nt < 4; ++nt)
#pragma unroll
      for (int mt = 0; mt < 4; ++mt) acc[nt][mt] = (f32x4){0.f, 0.f, 0.f, 0.f};
#pragma unroll
    for (int kc = 0; kc < 2; ++kc)
#pragma unroll
      for (int nt = 0; nt < 4; ++nt)
#pragma unroll
        for (int mt = 0; mt < 4; ++mt)
          acc[nt][mt] = __builtin_amdgcn_mfma_f32_16x16x32_f16(wf[nt][kc], af[mt][kc], acc[nt][mt], 0, 0, 0);

    float4 bl4[4];
#pragma unroll
    for (int nt = 0; nt < 4; ++nt) bl4[nt] = *(const float4*)&bias[nt * 16 + quad * 4];

#pragma unroll
    for (int mt = 0; mt < 4; ++mt) {
      const int g = m0 + mt * 16 + l15;   // (b*S+s)*H + h
#pragma unroll
      for (int nt = 0; nt < 4; ++nt) {
        const float p0 = (acc[nt][mt][0] + bl4[nt].x) * scale;
        const float p1 = (acc[nt][mt][1] + bl4[nt].y) * scale;
        const float p2 = (acc[nt][mt][2] + bl4[nt].z) * scale;
        const float p3 = (acc[nt][mt][3] + bl4[nt].w) * scale;
        union { f16x4 v4; f16x2 hh[2]; } u;
        u.hh[0] = __builtin_bit_cast(f16x2, __builtin_amdgcn_cvt_pkrtz(p0, p1));
        u.hh[1] = __builtin_bit_cast(f16x2, __builtin_amdgcn_cvt_pkrtz(p2, p3));
        if (vpass) {
          // tb[pi][sl]: pi = h*64 + d, h=l15, d=nt*16+quad*4+r, sl=w*4+mt
#pragma unroll
          for (int r = 0; r < 4; ++r)
            tb[(l15 * 64 + nt * 16 + quad * 4 + r) * 16 + w * 4 + mt] = u.v4[r];
        } else if (kpass) {
          // tb[h*16+sl][68]: coalesced-store bounce
          *(f16x4*)&tb[(l15 * 16 + w * 4 + mt) * 68 + nt * 16 + quad * 4] = u.v4;
        } else {
          // Q: natural layout [b][s][h][d] = row g -> coalesced
          *(f16x4*)(qp + (size_t)g * 64 + nt * 16 + quad * 4) = u.v4;
        }
      }
    }

    if (vpass) {
      __syncthreads();
      const int bsb = blockIdx.x * 16;
      const int bb = bsb >> 11;
      const int sb = bsb & 2047;
      const int off = sb & 63;                              // in {0,16,32,48}
      const int poff = (off & 32) | ((off & 16) >> 2);      // perm-inverse of the off bits
      const int col0 = (sb - off) + poff;
#pragma unroll
      for (int k2 = 0; k2 < 4; ++k2) {
        const int pi = t * 4 + k2;                          // (h,d) pair
        const int h = pi >> 6, d = pi & 63;
        const f16x8 lo = *(const f16x8*)&tb[pi * 16];
        const f16x8 hi = *(const f16x8*)&tb[pi * 16 + 8];
        f16* orow = vtp + ((size_t)(bb * H + h) * 64 + d) * S + col0;
        f16x4 g0, g1, g2, g3;
#pragma unroll
        for (int j = 0; j < 4; ++j) { g0[j]=lo[j]; g1[j]=lo[4+j]; g2[j]=hi[j]; g3[j]=hi[4+j]; }
        *(f16x4*)(orow + 0)  = g0;
        *(f16x4*)(orow + 8)  = g1;
        *(f16x4*)(orow + 16) = g2;
        *(f16x4*)(orow + 24) = g3;
      }
      __syncthreads();
    } else if (kpass) {
      __syncthreads();
      // writeout: thread t -> h = t>>4, sl = t&15: 64 contiguous f16 to kp[b][h][s][d]
      const int bsb = blockIdx.x * 16;
      const int bb = bsb >> 11;
      const int sblk = bsb & 2047;
      const int h = t >> 4, sl = t & 15;
      f16* dst = kp + ((size_t)(bb * H + h) * S + sblk + sl) * 64;
      const f16* src = &tb[t * 68];
#pragma unroll
      for (int c = 0; c < 8; ++c)
        *(f16x8*)(dst + c * 8) = *(const f16x8*)(src + c * 8);
    }
  }
}

// ---------- MFMA flash attention v8: KVBLK=128, depth-2 gload_lds staging, and the tile
// body split into 4 INDEPENDENT kv-chunks {QK(8 mfma) -> exp2/pack -> PV(10 mfma)} so the
// compiler can pipeline chunk i+1's QK under chunk i's exp2 (MFMA + trans pipes concurrent).
// V-read/write XOR widened to the full 4-bit row (fixes R7's 2.1M bank conflicts).
// pa[mt][j] = exp2(sc[j>>2][mt][j&3]) per chunk (verified mapping).
__global__ __launch_bounds__(256) void attn_mfma(const f16* __restrict__ qp,
                                                 const f16* __restrict__ kp,
                                                 const f16* __restrict__ vtp,
                                                 f16* __restrict__ ao) {
  __shared__ f16 ks[2][128 * 64];   // K tile [kv][d-chunks], LDS[r][c]=glob chunk c^(r&7)
  __shared__ f16 vs[2][64 * 128];   // V^T tile [d][p-chunks], LDS[r][c]=glob chunk c^(r&15)
  const int t = threadIdx.x, lane = t & 63, w = t >> 6;
  const int l15 = lane & 15, quad = lane >> 4;
  const int bh = blockIdx.x;
  const int b = bh >> 4, h = bh & 15;
  const int q0 = blockIdx.y * 128;
  const f16* kbase = kp + (size_t)bh * S * D;
  const f16* vtbase = vtp + (size_t)bh * 64 * S;

  // staging geometry: base chunk c1 = w*64 + lane; call i adds 256 chunks.
  const int c1 = w * 64 + lane;
  const int krow = c1 >> 3;                       // K: 8 chunks/row (row&7 preserved across i)
  const size_t koff1 = (size_t)krow * D + (((c1 & 7) ^ (krow & 7)) * 8);
  const int vrow = c1 >> 4;                       // V: 16 chunks/row (row&15 preserved across i)
  const size_t voff1 = (size_t)vrow * S + (((c1 & 15) ^ (vrow & 15)) * 8);

  f16x8 qf[2][2];
#pragma unroll
  for (int mt = 0; mt < 2; ++mt)
#pragma unroll
    for (int kc = 0; kc < 2; ++kc)
      qf[mt][kc] = *(const f16x8*)(qp +
          ((size_t)(b * S + q0 + w * 32 + mt * 16 + l15) * H + h) * 64 + kc * 32 + quad * 8);

  // ones-column B-frag: B[k][n]=1 for n==0 -> row-sum (l) accumulates in O[mt][4] col 0
  f16x8 vb4;
#pragma unroll
  for (int j = 0; j < 8; ++j) vb4[j] = (l15 == 0) ? (f16)1.0f : (f16)0.0f;

  f32x4 O[2][5];
#pragma unroll
  for (int mt = 0; mt < 2; ++mt)
#pragma unroll
    for (int nt = 0; nt < 5; ++nt) O[mt][nt] = (f32x4){0.f, 0.f, 0.f, 0.f};

#define ISSUE_TILE(tt, buf)                                                    \
  {                                                                            \
    const f16* gk = kbase + (size_t)(tt) * (128 * D);                          \
    _Pragma("unroll")                                                          \
    for (int i = 0; i < 4; ++i)                                                \
      GLOBAL_LOAD_LDS16(gk + koff1 + (size_t)i * (32 * D),                     \
                        &ks[buf][(i * 256 + w * 64) * 8]);                     \
    const f16* gv = vtbase + (size_t)(tt) * 128;                               \
    _Pragma("unroll")                                                          \
    for (int i = 0; i < 4; ++i)                                                \
      GLOBAL_LOAD_LDS16(gv + voff1 + (size_t)i * (16 * S),                     \
                        &vs[buf][(i * 256 + w * 64) * 8]);                     \
  }

  ISSUE_TILE(0, 0);

  for (int kt = 0; kt < S / 128; ++kt) {
    const int rb = kt & 1;
    // tile kt's loads (issued a full tile ago) complete; barrier closes reads of rb^1
    __asm__ volatile("s_waitcnt vmcnt(0)" ::: "memory");
    __builtin_amdgcn_s_barrier();
    __asm__ volatile("" ::: "memory");
    if (kt + 1 < S / 128) ISSUE_TILE(kt + 1, rb ^ 1);

    // 4 independent kv-chunks of 32: QK -> exp2/pack -> PV. Chunks pipeline against
    // each other (chunk i+1's QK is independent of chunk i's softmax/PV).
#pragma unroll
    for (int kc = 0; kc < 4; ++kc) {
      // QK^T swapped: sc[ntl][mt] = mfma(K-frag, Q-frag) -> C[kv][q], q=l15 lane-local
      f32x4 sc[2][2];
#pragma unroll
      for (int ntl = 0; ntl < 2; ++ntl)
#pragma unroll
        for (int mt = 0; mt < 2; ++mt) sc[ntl][mt] = (f32x4){0.f, 0.f, 0.f, 0.f};
      __builtin_amdgcn_s_setprio(1);
#pragma unroll
      for (int kcq = 0; kcq < 2; ++kcq)
#pragma unroll
        for (int ntl = 0; ntl < 2; ++ntl) {
          const int nt = kc * 2 + ntl;
          const f16x8 kf = *(const f16x8*)&ks[rb][(nt * 16 + l15) * 64 + (((kcq * 4 + quad) ^ (l15 & 7)) * 8)];
#pragma unroll
          for (int mt = 0; mt < 2; ++mt)
            sc[ntl][mt] = __builtin_amdgcn_mfma_f32_16x16x32_f16(kf, qf[mt][kcq], sc[ntl][mt], 0, 0, 0);
        }
      __builtin_amdgcn_s_setprio(0);

      // P = exp2(sc) packed into this chunk's PV A-frag (in-register)
      f16x8 pa[2];
#pragma unroll
      for (int mt = 0; mt < 2; ++mt) {
        const f32x4 s0 = sc[0][mt], s1 = sc[1][mt];
        union { f16x8 v8; f16x2 hh[4]; } u;
        u.hh[0] = __builtin_bit_cast(f16x2, __builtin_amdgcn_cvt_pkrtz(
            __builtin_amdgcn_exp2f(s0[0]), __builtin_amdgcn_exp2f(s0[1])));
        u.hh[1] = __builtin_bit_cast(f16x2, __builtin_amdgcn_cvt_pkrtz(
            __builtin_amdgcn_exp2f(s0[2]), __builtin_amdgcn_exp2f(s0[3])));
        u.hh[2] = __builtin_bit_cast(f16x2, __builtin_amdgcn_cvt_pkrtz(
            __builtin_amdgcn_exp2f(s1[0]), __builtin_amdgcn_exp2f(s1[1])));
        u.hh[3] = __builtin_bit_cast(f16x2, __builtin_amdgcn_cvt_pkrtz(
            __builtin_amdgcn_exp2f(s1[2]), __builtin_amdgcn_exp2f(s1[3])));
        pa[mt] = u.v8;
      }

      // PV += P * V for this chunk; l accumulates in O[mt][4] col 0
      __builtin_amdgcn_s_setprio(1);
#pragma unroll
      for (int nt = 0; nt < 4; ++nt) {
        const f16x8 vbf = *(const f16x8*)&vs[rb][(nt * 16 + l15) * 128 + (((kc * 4 + quad) ^ l15) * 8)];
#pragma unroll
        for (int mt = 0; mt < 2; ++mt)
          O[mt][nt] = __builtin_amdgcn_mfma_f32_16x16x32_f16(pa[mt], vbf, O[mt][nt], 0, 0, 0);
      }
#pragma unroll
      for (int mt = 0; mt < 2; ++mt)
        O[mt][4] = __builtin_amdgcn_mfma_f32_16x16x32_f16(pa[mt], vb4, O[mt][4], 0, 0, 0);
      __builtin_amdgcn_s_setprio(0);
    }
  }
#undef ISSUE_TILE

  // epilogue: l lives in lane group's l15==0 lane of O[mt][4]
#pragma unroll
  for (int mt = 0; mt < 2; ++mt)
#pragma unroll
    for (int r = 0; r < 4; ++r) {
      const float l = __shfl(O[mt][4][r], quad << 4, 64);
      const float inv = 1.f / l;
      const int row = q0 + w * 32 + mt * 16 + quad * 4 + r;
      f16* o = ao + ((size_t)b * S + row) * E + h * D;
#pragma unroll
      for (int nt = 0; nt < 4; ++nt)
        o[nt * 16 + l15] = (f16)(O[mt][nt][r] * inv);
    }
}

// ---------- dense: out[m][n] = sum_e A[m][e] * Wd16[n][e] + bd[n]
// BM=128, BN=64, triple-buffered, counted vmcnt(6) + raw barrier. 2 blocks/CU.
__global__ __launch_bounds__(256) void dense_mfma(const f16* __restrict__ A,
                                                  const f16* __restrict__ Wd16,
                                                  const float* __restrict__ bd,
                                                  float* __restrict__ out) {
  __shared__ f16 as[3][128 * 64];   // 48 KB
  __shared__ f16 bs[3][64 * 64];    // 24 KB
  const int t = threadIdx.x;
  const int lane = t & 63;
  const int w = t >> 6;
  const int l15 = lane & 15;
  const int quad = lane >> 4;
  const int m0 = blockIdx.x * 128;
  const int n0 = blockIdx.y * 64;
  const int wm = (w >> 1) * 64, wn = (w & 1) * 32;   // wave tile 64x32

  const int srow = (lane >> 3);
  const int schunk = (lane & 7) ^ srow;
  const f16* ga0 = A    + (size_t)(m0 + w * 32 + srow) * E + schunk * 8;
  const f16* gb0 = Wd16 + (size_t)(n0 + w * 16 + srow) * E + schunk * 8;

  constexpr int NT = E / 64;

#define ISSUE_D(tt, ib)                                                        \
  {                                                                            \
    _Pragma("unroll")                                                          \
    for (int i = 0; i < 4; ++i)                                                \
      GLOBAL_LOAD_LDS16(ga0 + (size_t)(i * 8) * E + (tt) * 64,                 \
                        &as[ib][(w * 32 + i * 8) * 64]);                       \
    _Pragma("unroll")                                                          \
    for (int i = 0; i < 2; ++i)                                                \
      GLOBAL_LOAD_LDS16(gb0 + (size_t)(i * 8) * E + (tt) * 64,                 \
                        &bs[ib][(w * 16 + i * 8) * 64]);                       \
  }

  f32x4 acc[4][2];
#pragma unroll
  for (int mt = 0; mt < 4; ++mt)
#pragma unroll
    for (int nt = 0; nt < 2; ++nt) acc[mt][nt] = (f32x4){0.f, 0.f, 0.f, 0.f};

  ISSUE_D(0, 0);
  ISSUE_D(1, 1);
  __asm__ volatile("s_waitcnt vmcnt(6)" ::: "memory");
  __builtin_amdgcn_s_barrier();
  __asm__ volatile("" ::: "memory");

  int rb = 0, ib = 2;
  for (int kt = 0; kt < NT; ++kt) {
    {
      const int tt = (kt + 2 < NT) ? (kt + 2) : (NT - 1);
      ISSUE_D(tt, ib);
    }
    f16x8 af[4][2];
#pragma unroll
    for (int mt = 0; mt < 4; ++mt)
#pragma unroll
      for (int kc = 0; kc < 2; ++kc)
        af[mt][kc] = *(const f16x8*)&as[rb][(wm + mt * 16 + l15) * 64 + (((kc * 4 + quad) ^ (l15 & 7)) * 8)];
#pragma unroll
    for (int kc = 0; kc < 2; ++kc)
#pragma unroll
      for (int nt = 0; nt < 2; ++nt) {
        const f16x8 bf = *(const f16x8*)&bs[rb][(wn + nt * 16 + l15) * 64 + (((kc * 4 + quad) ^ (l15 & 7)) * 8)];
#pragma unroll
        for (int mt = 0; mt < 4; ++mt)
          acc[mt][nt] = __builtin_amdgcn_mfma_f32_16x16x32_f16(af[mt][kc], bf, acc[mt][nt], 0, 0, 0);
      }
    __asm__ volatile("s_waitcnt vmcnt(6)" ::: "memory");
    __builtin_amdgcn_s_barrier();
    __asm__ volatile("" ::: "memory");
    rb = (rb + 1 >= 3) ? 0 : rb + 1;
    ib = (ib + 1 >= 3) ? 0 : ib + 1;
  }
#undef ISSUE_D

#pragma unroll
  for (int nt = 0; nt < 2; ++nt) {
    const int col = n0 + wn + nt * 16 + l15;
    const float bdv = bd[col];
#pragma unroll
    for (int mt = 0; mt < 4; ++mt)
#pragma unroll
      for (int r = 0; r < 4; ++r)
        out[(size_t)(m0 + wm + mt * 16 + quad * 4 + r) * E + col] = acc[mt][nt][r] + bdv;
  }
}

extern "C" void kernel_launch(void* const* d_in, const int* in_sizes, int n_in,
                              void* d_out, int out_size, void* d_ws, size_t ws_size,
                              hipStream_t stream) {
  const float* queries = (const float*)d_in[0];
  const float* values  = (const float*)d_in[1];
  const float* Wv = (const float*)d_in[3];
  const float* bv = (const float*)d_in[4];
  const float* Wk = (const float*)d_in[5];
  const float* bk = (const float*)d_in[6];
  const float* Wq = (const float*)d_in[7];
  const float* bq = (const float*)d_in[8];
  const float* Wd = (const float*)d_in[9];
  const float* bd = (const float*)d_in[10];
  float* out = (float*)d_out;

  char* ws = (char*)d_ws;
  f16* qp    = (f16*)(ws);                          // 8 MB [B,S,H,D]  (natural layout)
  f16* kp    = (f16*)(ws + 8u * 1024 * 1024);       // 8 MB [B,H,S,D]
  f16* vtp   = (f16*)(ws + 16u * 1024 * 1024);      // 8 MB [B,H,D,S] permuted V^T
  f16* ao    = (f16*)(ws + 24u * 1024 * 1024);      // 8 MB [B,S,E]
  f16* wd16  = (f16*)(ws + 32u * 1024 * 1024);      // 2 MB
  float* wkv = (float*)(ws + 34u * 1024 * 1024);    // 16 KB
  float* bkv = (float*)(ws + 34u * 1024 * 1024 + 16384);
  (void)ws_size; (void)in_sizes; (void)n_in; (void)out_size;

  prep<<<1040, 256, 0, stream>>>(Wd, wd16, Wk, Wv, bv, bk, wkv, bkv);
  proj3_mfma<<<dim3(256, 2), 256, 0, stream>>>(queries, values, Wq, bq, Wv, bv, wkv, bkv, qp, vtp, kp);
  attn_mfma<<<dim3(B * H, S / 128), 256, 0, stream>>>(qp, kp, vtp, ao);
  dense_mfma<<<dim3(B * S / 128, E / 64), 256, 0, stream>>>(ao, wd16, bd, out);
}